// Round 7
// baseline (230.043 us; speedup 1.0000x reference)
//
#include <hip/hip_runtime.h>
#include <cmath>

#define NPTS 262144
#define NLVL 16
#define NDENSE 5
#define NHASH 11
#define HASH_MASK 0x7FFFFu
#define P2 2654435761u
#define P3 805459861u

// levels 0+1 table region: 4096 + 12168 entries, contiguous at emb[0:32528]
#define DENSE01_F4 8132          // 32528 floats / 4
#define DENSE01_BYTES 130112

typedef float v2f __attribute__((ext_vector_type(2)));
typedef float v3f __attribute__((ext_vector_type(3), aligned(4)));
typedef float v4f __attribute__((ext_vector_type(4)));
// 16B vector with 8B alignment (dense pair loads are only 8B-aligned)
typedef float v4f8 __attribute__((ext_vector_type(4), aligned(8)));

struct MetaD { float scale[NDENSE]; unsigned off[NDENSE]; unsigned res[NDENSE]; };
struct MetaH { float scale[NHASH]; unsigned off[NHASH]; };

struct Pt { float x, y, z; };
struct Prep { unsigned idx[8]; float fx, fy, fz; };

// plain dwordx3 means load: 1 coalesced request; L2 retains means for the 11 re-reads
__device__ __forceinline__ Pt load_pt(const float* __restrict__ means, int p) {
    const v3f m = *(const v3f*)(means + 3 * p);
    Pt q;
    q.x = (m.x + 1.0f) * 0.5f;
    q.y = (m.y + 1.0f) * 0.5f;
    q.z = (m.z + 1.0f) * 0.5f;
    return q;
}

// hash index prep (hsize = 2^19) — off folded into idx; branch-free (R1 exact)
__device__ __forceinline__ Prep hprep(Pt q, float s, unsigned off) {
    const float px = q.x * s, py = q.y * s, pz = q.z * s;
    const float gx = floorf(px), gy = floorf(py), gz = floorf(pz);
    Prep d;
    d.fx = px - gx; d.fy = py - gy; d.fz = pz - gz;
    const unsigned ix = (unsigned)gx, iy = (unsigned)gy, iz = (unsigned)gz;
    const unsigned hy0 = iy * P2, hy1 = hy0 + P2;
    const unsigned hz0 = iz * P3, hz1 = hz0 + P3;
    const unsigned h0 = hy0 ^ hz0, h1 = hy1 ^ hz0, h2 = hy0 ^ hz1, h3 = hy1 ^ hz1;
    d.idx[0] = ((ix ^ h0) & HASH_MASK) + off; d.idx[1] = (((ix + 1u) ^ h0) & HASH_MASK) + off;
    d.idx[2] = ((ix ^ h1) & HASH_MASK) + off; d.idx[3] = (((ix + 1u) ^ h1) & HASH_MASK) + off;
    d.idx[4] = ((ix ^ h2) & HASH_MASK) + off; d.idx[5] = (((ix + 1u) ^ h2) & HASH_MASK) + off;
    d.idx[6] = ((ix ^ h3) & HASH_MASK) + off; d.idx[7] = (((ix + 1u) ^ h3) & HASH_MASK) + off;
    return d;
}

__device__ __forceinline__ v2f trilerp(const v2f* f, float fx, float fy, float fz) {
    const float wx0 = 1.0f - fx, wy0 = 1.0f - fy, wz0 = 1.0f - fz;
    const float w00 = wz0 * wy0, w01 = wz0 * fy, w10 = fz * wy0, w11 = fz * fy;
    return w00 * (wx0 * f[0] + fx * f[1]) + w01 * (wx0 * f[2] + fx * f[3])
         + w10 * (wx0 * f[4] + fx * f[5]) + w11 * (wx0 * f[6] + fx * f[7]);
}

// ---------------- hash levels 5..15, XCD-affine, 704 balanced jobs/XCD (proven body) ----------------
__global__ __launch_bounds__(256) void enc_hash(
    const float* __restrict__ means, const float* __restrict__ emb,
    v2f* __restrict__ dst, int lvl_major, MetaH meta)
{
    const unsigned b = blockIdx.x;
    const unsigned xcd = b & 7u, slot = b >> 3;
    unsigned il, chunk;
    if (slot < 512u) { il = xcd; chunk = slot; }
    else {
        const unsigned g = xcd * 192u + (slot - 512u);   // 0..1535 over levels 8..10
        il = 8u + (g >> 9);
        chunk = g & 511u;
    }
    const float s = meta.scale[il];
    const unsigned off = meta.off[il];
    const unsigned lvl = il + NDENSE;
    const int p0 = (int)(chunk * 512u + threadIdx.x);
    const v2f* __restrict__ emb2 = (const v2f*)emb;

    const Prep A = hprep(load_pt(means, p0), s, off);
    v2f fa[8];
#pragma unroll
    for (int k = 0; k < 8; ++k) fa[k] = emb2[A.idx[k]];
    const Prep B = hprep(load_pt(means, p0 + 256), s, off);
    v2f fb[8];
#pragma unroll
    for (int k = 0; k < 8; ++k) fb[k] = emb2[B.idx[k]];

    const v2f ra = trilerp(fa, A.fx, A.fy, A.fz);
    const size_t diA = lvl_major ? ((size_t)lvl * NPTS + p0) : ((size_t)p0 * NLVL + lvl);
    dst[diA] = ra;
    const v2f rb = trilerp(fb, B.fx, B.fy, B.fz);
    const size_t diB = lvl_major ? ((size_t)lvl * NPTS + (p0 + 256)) : ((size_t)(p0 + 256) * NLVL + lvl);
    dst[diB] = rb;
}

// dense level body shared by both finalize variants; LDS2 may be null (all-global)
__device__ __forceinline__ v2f dense_level(
    const Pt& q, const float* __restrict__ emb, const v2f* __restrict__ lds2,
    bool use_lds, float s, unsigned r, unsigned off)
{
    const float px = q.x * s, py = q.y * s, pz = q.z * s;
    const float gx = floorf(px), gy = floorf(py), gz = floorf(pz);
    const float fx = px - gx, fy = py - gy, fz = pz - gz;
    const unsigned dy = r, dz = r * r;
    const unsigned base = (unsigned)gx + (unsigned)gy * dy + (unsigned)gz * dz + off;

    const float wx0 = 1.0f - fx, wy0 = 1.0f - fy, wz0 = 1.0f - fz;
    const float wc[4] = {wz0 * wy0, wz0 * fy, fz * wy0, fz * fy};
    v2f acc = {0.0f, 0.0f};
    if (use_lds) {
        // divergent reads on the (idle) LDS pipe instead of the saturated TA pipe
        const unsigned bi[4] = {base, base + dy, base + dz, base + dz + dy};
#pragma unroll
        for (int c = 0; c < 4; ++c)
            acc += wc[c] * (wx0 * lds2[bi[c]] + fx * lds2[bi[c] + 1]);
    } else {
        v4f8 F[4];
        F[0] = *(const v4f8*)(emb + 2u * base);
        F[1] = *(const v4f8*)(emb + 2u * (base + dy));
        F[2] = *(const v4f8*)(emb + 2u * (base + dz));
        F[3] = *(const v4f8*)(emb + 2u * (base + dz + dy));
#pragma unroll
        for (int c = 0; c < 4; ++c)
            acc += wc[c] * (wx0 * (v2f){F[c].x, F[c].y} + fx * (v2f){F[c].z, F[c].w});
    }
    return acc;
}

// ---------------- finalize with LDS-staged levels 0+1 (130KB dynamic LDS, 1024 thr) ----------------
__global__ __launch_bounds__(1024) void finalize_lds(
    const float* __restrict__ means, const float* __restrict__ emb,
    const v2f* __restrict__ ws, float* __restrict__ out, MetaD meta)
{
    extern __shared__ float lds[];
    const int t = threadIdx.x;
    {
        const v4f* __restrict__ src4 = (const v4f*)emb;
        v4f* dst4 = (v4f*)lds;
#pragma unroll
        for (int k = 0; k < 8; ++k) {
            const int i = t + (k << 10);
            if (i < DENSE01_F4) dst4[i] = src4[i];
        }
    }
    __syncthreads();
    const v2f* __restrict__ lds2 = (const v2f*)lds;

    const int p = blockIdx.x * 1024 + t;

    v2f h[NHASH];
#pragma unroll
    for (int l = 0; l < NHASH; ++l)
        h[l] = ws[(size_t)(NDENSE + l) * NPTS + p];

    const Pt q = load_pt(means, p);

    v4f o[8];
    v2f* o2 = (v2f*)o;
#pragma unroll
    for (int l = 0; l < NDENSE; ++l)
        o2[l] = dense_level(q, emb, lds2, l < 2, meta.scale[l], meta.res[l], meta.off[l]);
#pragma unroll
    for (int l = 0; l < NHASH; ++l)
        o2[NDENSE + l] = h[l];

    v4f* out4 = (v4f*)(out + (size_t)p * (2 * NLVL));
#pragma unroll
    for (int k = 0; k < 8; ++k)
        __builtin_nontemporal_store(o[k], &out4[k]);   // write-only stream
}

// ---------------- all-global finalize fallback (R6 body) ----------------
__global__ __launch_bounds__(256) void finalize_g(
    const float* __restrict__ means, const float* __restrict__ emb,
    const v2f* __restrict__ ws, float* __restrict__ out, MetaD meta)
{
    const int p = blockIdx.x * 256 + threadIdx.x;

    v2f h[NHASH];
#pragma unroll
    for (int l = 0; l < NHASH; ++l)
        h[l] = ws[(size_t)(NDENSE + l) * NPTS + p];

    const Pt q = load_pt(means, p);

    v4f o[8];
    v2f* o2 = (v2f*)o;
#pragma unroll
    for (int l = 0; l < NDENSE; ++l)
        o2[l] = dense_level(q, emb, nullptr, false, meta.scale[l], meta.res[l], meta.off[l]);
#pragma unroll
    for (int l = 0; l < NHASH; ++l)
        o2[NDENSE + l] = h[l];

    v4f* out4 = (v4f*)(out + (size_t)p * (2 * NLVL));
#pragma unroll
    for (int k = 0; k < 8; ++k)
        __builtin_nontemporal_store(o[k], &out4[k]);
}

// ---------------- fallback dense (point-major direct-to-out) ----------------
__global__ __launch_bounds__(256) void enc_dense(
    const float* __restrict__ means, const float* __restrict__ emb,
    v2f* __restrict__ dst, int lvl_major, MetaD meta)
{
    const int p = blockIdx.x * 256 + threadIdx.x;
    const int l = blockIdx.y;
    const Pt q = load_pt(means, p);
    const v2f res = dense_level(q, emb, nullptr, false, meta.scale[l], meta.res[l], meta.off[l]);
    const size_t di = lvl_major ? ((size_t)l * NPTS + p) : ((size_t)p * NLVL + l);
    dst[di] = res;
}

extern "C" void kernel_launch(void* const* d_in, const int* in_sizes, int n_in,
                              void* d_out, int out_size, void* d_ws, size_t ws_size,
                              hipStream_t stream)
{
    const float* means = (const float*)d_in[0];
    const float* emb   = (const float*)d_in[1];
    float* out         = (float*)d_out;

    MetaD md;
    MetaH mh;
    const double lg = log2(1.38191288);
    unsigned off = 0;
    for (int l = 0; l < NLVL; ++l) {
        const double scale_d = pow(2.0, (double)l * lg) * 16.0 - 1.0;
        const unsigned res_enc = (unsigned)ceil(scale_d) + 1u;

        const double gres_d = ceil(16.0 * pow(1.38191288, (double)l));
        unsigned long long r3 = (unsigned long long)gres_d;
        r3 = r3 * r3 * r3;
        unsigned long long pl = r3 < (1ull << 19) ? r3 : (1ull << 19);
        pl = (pl + 7ull) / 8ull * 8ull;

        if (l < NDENSE) {
            md.scale[l] = (float)scale_d;
            md.off[l]   = off;
            md.res[l]   = res_enc;
        } else {
            mh.scale[l - NDENSE] = (float)scale_d;
            mh.off[l - NDENSE]   = off;
        }
        off += (unsigned)pl;
    }

    // one-time opt-in to >64KB dynamic LDS (host-side attribute set; graph-safe)
    static int lds_ok = -1;
    if (lds_ok < 0) {
        lds_ok = (hipFuncSetAttribute((const void*)finalize_lds,
                                      hipFuncAttributeMaxDynamicSharedMemorySize,
                                      DENSE01_BYTES) == hipSuccess) ? 1 : 0;
    }

    const size_t ws_needed = (size_t)NLVL * NPTS * sizeof(float) * 2;  // 32 MB
    const bool use_ws = ws_size >= ws_needed;

    if (use_ws) {
        v2f* wsp = (v2f*)d_ws;
        enc_hash<<<dim3(8 * 704, 1, 1), 256, 0, stream>>>(means, emb, wsp, 1, mh);
        if (lds_ok)
            finalize_lds<<<NPTS / 1024, 1024, DENSE01_BYTES, stream>>>(means, emb, (const v2f*)wsp, out, md);
        else
            finalize_g<<<NPTS / 256, 256, 0, stream>>>(means, emb, (const v2f*)wsp, out, md);
    } else {
        v2f* dst = (v2f*)out;
        enc_dense<<<dim3(NPTS / 256, NDENSE, 1), 256, 0, stream>>>(means, emb, dst, 0, md);
        enc_hash <<<dim3(8 * 704, 1, 1),          256, 0, stream>>>(means, emb, dst, 0, mh);
    }
}